// Round 9
// baseline (268.812 us; speedup 1.0000x reference)
//
#include <hip/hip_runtime.h>
#include <cstddef>

#define B_    16
#define SQ_   1024
#define SE_   1024
#define CIN_  256
#define DK_   64
#define H_    8
#define HD_   512
#define NROWS 16384
#define BN_EPS 1e-5f
#define NEG_SLOPE 0.01f

typedef __attribute__((ext_vector_type(8))) short bf16x8;
typedef __attribute__((ext_vector_type(4))) float f32x4;

__device__ __forceinline__ unsigned short f2bf(float f) {  // RNE
    unsigned int u = __float_as_uint(f);
    return (unsigned short)((u + 0x7FFFu + ((u >> 16) & 1u)) >> 16);
}

#if __has_builtin(__builtin_amdgcn_perm)
__device__ __forceinline__ unsigned int pack_trunc(float lo, float hi) {
    return __builtin_amdgcn_perm(__float_as_uint(hi), __float_as_uint(lo), 0x07060302u);
}
#else
__device__ __forceinline__ unsigned int pack_trunc(float lo, float hi) {
    return (__float_as_uint(lo) >> 16) | (__float_as_uint(hi) & 0xFFFF0000u);
}
#endif

#if __has_builtin(__builtin_amdgcn_exp2f)
#define EXP2F(x) __builtin_amdgcn_exp2f(x)
#else
#define EXP2F(x) exp2f(x)
#endif

__device__ __forceinline__ ushort4 pack4(f32x4 v) {
    ushort4 p;
    p.x = f2bf(v[0]); p.y = f2bf(v[1]);
    p.z = f2bf(v[2]); p.w = f2bf(v[3]);
    return p;
}

// ---------------------------------------------------------------------------
// Weight casts (one dispatch). Wq gets 0.125*log2(e) folded in.
// Blocks 0..1 also zero the BN stats accumulators.
// ---------------------------------------------------------------------------
__global__ __launch_bounds__(256) void wcast(const float* __restrict__ Wq,
                                             const float* __restrict__ Wk,
                                             const float* __restrict__ Wv,
                                             const float* __restrict__ Wp,
                                             unsigned short* __restrict__ dWq,
                                             unsigned short* __restrict__ dWkv,
                                             unsigned short* __restrict__ dWp,
                                             float* __restrict__ stats) {
    if (blockIdx.x < 2) stats[blockIdx.x * 256 + threadIdx.x] = 0.f;
    int i = blockIdx.x * 256 + threadIdx.x;
    int which = i >> 15, off = i & 32767;
    const float* s; unsigned short* d; float sc = 1.0f;
    if (which == 0)      { s = Wq; d = dWq; sc = 0.18033688011112042f; }
    else if (which == 1) { s = Wk; d = dWkv; }
    else if (which == 2) { s = Wv; d = dWkv + 131072; }
    else                 { s = Wp; d = dWp; }
    float4 v = *(const float4*)(s + (size_t)off * 4);
    ushort4 pk;
    pk.x = f2bf(v.x * sc); pk.y = f2bf(v.y * sc);
    pk.z = f2bf(v.z * sc); pk.w = f2bf(v.w * sc);
    *(ushort4*)(d + (size_t)off * 4) = pk;
}

// ---------------------------------------------------------------------------
// q / x fp32 -> bf16 pre-cast, one dispatch (memory-bound).
// ---------------------------------------------------------------------------
__global__ __launch_bounds__(256) void qx_cast(const float* __restrict__ q,
                                               const float* __restrict__ x,
                                               unsigned short* __restrict__ qbf,
                                               unsigned short* __restrict__ xbf) {
    int i = blockIdx.x * 256 + threadIdx.x;    // float4 index, 2*1048576 total
    const float* s = (i < 1048576) ? q : x;
    unsigned short* d = (i < 1048576) ? qbf : xbf;
    int off = i & 1048575;
    float4 v = *(const float4*)(s + (size_t)off * 4);
    ushort4 pk;
    pk.x = f2bf(v.x); pk.y = f2bf(v.y);
    pk.z = f2bf(v.z); pk.w = f2bf(v.w);
    *(ushort4*)(d + (size_t)off * 4) = pk;
}

// ---------------------------------------------------------------------------
// Fused Q+KV projection GEMM, 128x128 tile (wave owns 32x128), BK=64,
// bf16 A (pre-cast), register prefetch. grid (12,128): bx<4 Q-proj,
// bx 4..7 K-proj, bx 8..11 V-proj.
// Q/K use TRANSPOSED compute mfma(W,A) -> reg index runs along output col
// -> packed ushort4 stores. V uses normal orientation (vT output already
// transposed: reg index runs along t).
// ---------------------------------------------------------------------------
__global__ __launch_bounds__(256) void gemm_qkv3(const unsigned short* __restrict__ qbf,
                                                 const unsigned short* __restrict__ xbf,
                                                 const unsigned short* __restrict__ Wqb,
                                                 const unsigned short* __restrict__ Wkvb,
                                                 unsigned short* __restrict__ qh,
                                                 unsigned short* __restrict__ khb,
                                                 unsigned short* __restrict__ vTb) {
    __shared__ __align__(16) unsigned short As[128 * 72];   // 18 KB
    __shared__ __align__(16) unsigned short Ws[128 * 72];   // 18 KB
    const int tid = threadIdx.x;
    const int w = tid >> 6, l = tid & 63, lq = l >> 4, lr = l & 15;
    const int bx = blockIdx.x;
    const bool isQ = bx < 4;
    const bool isV = bx >= 8;
    const unsigned short* A = isQ ? qbf : xbf;
    const unsigned short* W = isQ ? Wqb : Wkvb;
    const int n0 = (isQ ? bx : bx - 4) * 128;
    const int m0 = blockIdx.y * 128;
    const int K = 256;

    const int srow = tid >> 1, soff = (tid & 1) * 32;   // 32 shorts/thread

    f32x4 acc[2][8] = {};
    uint4 aR[4], wR[4];

    {
        const unsigned short* Ar = A + (size_t)(m0 + srow) * K + soff;
        const unsigned short* Wr = W + (size_t)(n0 + srow) * K + soff;
        #pragma unroll
        for (int c = 0; c < 4; ++c) {
            aR[c] = *(const uint4*)(Ar + c * 8);
            wR[c] = *(const uint4*)(Wr + c * 8);
        }
    }

    for (int k0 = 0; k0 < K; k0 += 64) {
        __syncthreads();
        #pragma unroll
        for (int c = 0; c < 4; ++c) {
            *(uint4*)&As[srow * 72 + soff + c * 8] = aR[c];
            *(uint4*)&Ws[srow * 72 + soff + c * 8] = wR[c];
        }
        if (k0 + 64 < K) {
            const unsigned short* Ar = A + (size_t)(m0 + srow) * K + k0 + 64 + soff;
            const unsigned short* Wr = W + (size_t)(n0 + srow) * K + k0 + 64 + soff;
            #pragma unroll
            for (int c = 0; c < 4; ++c) {
                aR[c] = *(const uint4*)(Ar + c * 8);
                wR[c] = *(const uint4*)(Wr + c * 8);
            }
        }
        __syncthreads();

        if (!isV) {   // transposed compute: D[n][m]
            #pragma unroll
            for (int ks = 0; ks < 2; ++ks) {
                bf16x8 a0 = *(bf16x8*)&As[(w * 32 + lr) * 72 + ks * 32 + lq * 8];
                bf16x8 a1 = *(bf16x8*)&As[(w * 32 + 16 + lr) * 72 + ks * 32 + lq * 8];
                #pragma unroll
                for (int j = 0; j < 8; ++j) {
                    bf16x8 bb = *(bf16x8*)&Ws[(j * 16 + lr) * 72 + ks * 32 + lq * 8];
                    acc[0][j] = __builtin_amdgcn_mfma_f32_16x16x32_bf16(bb, a0, acc[0][j], 0, 0, 0);
                    acc[1][j] = __builtin_amdgcn_mfma_f32_16x16x32_bf16(bb, a1, acc[1][j], 0, 0, 0);
                }
            }
        } else {      // normal compute: D[m][n]
            #pragma unroll
            for (int ks = 0; ks < 2; ++ks) {
                bf16x8 a0 = *(bf16x8*)&As[(w * 32 + lr) * 72 + ks * 32 + lq * 8];
                bf16x8 a1 = *(bf16x8*)&As[(w * 32 + 16 + lr) * 72 + ks * 32 + lq * 8];
                #pragma unroll
                for (int j = 0; j < 8; ++j) {
                    bf16x8 bb = *(bf16x8*)&Ws[(j * 16 + lr) * 72 + ks * 32 + lq * 8];
                    acc[0][j] = __builtin_amdgcn_mfma_f32_16x16x32_bf16(a0, bb, acc[0][j], 0, 0, 0);
                    acc[1][j] = __builtin_amdgcn_mfma_f32_16x16x32_bf16(a1, bb, acc[1][j], 0, 0, 0);
                }
            }
        }
    }

    if (!isV) {
        // Transposed D: row = n_local = lq*4+r, col = m_local = lr.
        // Lane stores 4 consecutive output cols (n) at row m -> ushort4.
        unsigned short* C = isQ ? qh : khb;
        #pragma unroll
        for (int mf = 0; mf < 2; ++mf)
            #pragma unroll
            for (int j = 0; j < 8; ++j)
                *(ushort4*)&C[(size_t)(m0 + w * 32 + mf * 16 + lr) * 512 +
                              n0 + j * 16 + lq * 4] = pack4(acc[mf][j]);
    } else {
        // Normal D: row = m_local = lq*4+r (t dim), col = n = lr (e dim).
        #pragma unroll
        for (int mf = 0; mf < 2; ++mf) {
            int row = m0 + w * 32 + mf * 16 + lq * 4;
            int bb = row >> 10, t = row & 1023;
            #pragma unroll
            for (int j = 0; j < 8; ++j) {
                int colv = n0 - 512 + j * 16 + lr;
                int hh = colv >> 6, e = colv & 63;
                *(ushort4*)&vTb[(size_t)((bb * 8 + hh) * 64 + e) * 1024 + t] =
                    pack4(acc[mf][j]);
            }
        }
    }
}

// ---------------------------------------------------------------------------
// MFMA flash attention v7 = R3 staging skeleton (LDS K/V, two barriers) +
// S^T mfma(K,Q) + packed-b64 P writes + TRANSPOSED PV mfma(V,P): reg index
// runs along e -> packed ushort4 o-stores, and l_i lands on the owning lane
// (m = lane&15) -> scalar inv, no broadcast shuffles.
// ---------------------------------------------------------------------------
__global__ __launch_bounds__(256) void attn_mfma7(const unsigned short* __restrict__ qh,
                                                  const unsigned short* __restrict__ kh,
                                                  const unsigned short* __restrict__ vT,
                                                  unsigned short* __restrict__ o) {
    __shared__ __align__(16) unsigned short Ks[64 * 72];      // [key][d]
    __shared__ __align__(16) unsigned short Vs[64 * 72];      // [e][t]
    __shared__ __align__(16) unsigned short Ps[4][32 * 72];   // per-wave P [m][t]

    const int tid = threadIdx.x;
    const int w = tid >> 6, l = tid & 63, lq = l >> 4, lr = l & 15;
    const int q0 = blockIdx.x * 128, h = blockIdx.y, b = blockIdx.z;

    // Q fragments: lane lr holds row m, elems k = lq*8 + j (+32 for ks=1)
    bf16x8 qf[2][2];
    #pragma unroll
    for (int m = 0; m < 2; ++m) {
        const unsigned short* qr =
            qh + (size_t)(b * SQ_ + q0 + w * 32 + m * 16 + lr) * HD_ + h * DK_;
        qf[m][0] = *(const bf16x8*)(qr + lq * 8);
        qf[m][1] = *(const bf16x8*)(qr + 32 + lq * 8);
    }

    const unsigned short* kb = kh + (size_t)(b * SE_) * HD_ + h * DK_;
    const unsigned short* vb = vT + (size_t)((b * 8 + h) * 64) * 1024;

    const int se = tid >> 3;        // 0..31
    const int sc = (tid & 7) * 8;

    float l_i[2] = {};              // per-lane partial row-sum; m = mm*16 + lr
    f32x4 oacc[2][4] = {};          // [mm][e-strip j]; D[e][m]
    unsigned short* Pw = Ps[w];

    for (int t0 = 0; t0 < SE_; t0 += 64) {
        __syncthreads();
        #pragma unroll
        for (int ps = 0; ps < 2; ++ps) {
            int rr = se + ps * 32;
            *(uint4*)&Ks[rr * 72 + sc] = *(const uint4*)(kb + (size_t)(t0 + rr) * HD_ + sc);
            *(uint4*)&Vs[rr * 72 + sc] = *(const uint4*)(vb + (size_t)rr * 1024 + t0 + sc);
        }
        __syncthreads();

        // S^T tiles: sT[tt][mm]; C row = t (lq*4+r), col = m (lr)
        f32x4 sT[4][2] = {};
        #pragma unroll
        for (int ks = 0; ks < 2; ++ks)
            #pragma unroll
            for (int tt = 0; tt < 4; ++tt) {
                bf16x8 kf = *(bf16x8*)&Ks[(tt * 16 + lr) * 72 + ks * 32 + lq * 8];
                sT[tt][0] = __builtin_amdgcn_mfma_f32_16x16x32_bf16(kf, qf[0][ks], sT[tt][0], 0, 0, 0);
                sT[tt][1] = __builtin_amdgcn_mfma_f32_16x16x32_bf16(kf, qf[1][ks], sT[tt][1], 0, 0, 0);
            }

        // exp2 + lane-local l accum + packed b64 P write (4 consecutive t)
        #pragma unroll
        for (int mm = 0; mm < 2; ++mm)
            #pragma unroll
            for (int tt = 0; tt < 4; ++tt) {
                float e0 = EXP2F(sT[tt][mm][0]);
                float e1 = EXP2F(sT[tt][mm][1]);
                float e2 = EXP2F(sT[tt][mm][2]);
                float e3 = EXP2F(sT[tt][mm][3]);
                l_i[mm] += (e0 + e1) + (e2 + e3);
                uint2 pk;
                pk.x = pack_trunc(e0, e1);
                pk.y = pack_trunc(e2, e3);
                *(uint2*)&Pw[(mm * 16 + lr) * 72 + tt * 16 + lq * 4] = pk;
            }
        asm volatile("s_waitcnt lgkmcnt(0)" ::: "memory");   // wave-local round trip

        // PV transposed: oacc[mm][j] = V_strip_j . P_mm^T -> D[e][m]
        #pragma unroll
        for (int ks = 0; ks < 2; ++ks) {
            bf16x8 pf0 = *(bf16x8*)&Pw[(lr) * 72 + ks * 32 + lq * 8];
            bf16x8 pf1 = *(bf16x8*)&Pw[(16 + lr) * 72 + ks * 32 + lq * 8];
            #pragma unroll
            for (int j = 0; j < 4; ++j) {
                bf16x8 vf = *(bf16x8*)&Vs[(j * 16 + lr) * 72 + ks * 32 + lq * 8];
                oacc[0][j] = __builtin_amdgcn_mfma_f32_16x16x32_bf16(vf, pf0, oacc[0][j], 0, 0, 0);
                oacc[1][j] = __builtin_amdgcn_mfma_f32_16x16x32_bf16(vf, pf1, oacc[1][j], 0, 0, 0);
            }
        }
    }

    // Row sums: quad reduction puts the full sum for m = mm*16+lr on this
    // lane -- exactly the m this lane's oacc columns belong to.
    float inv[2];
    #pragma unroll
    for (int mm = 0; mm < 2; ++mm) {
        float t = l_i[mm];
        t += __shfl_xor(t, 16);
        t += __shfl_xor(t, 32);
        inv[mm] = 1.0f / t;
    }

    // o store: D row = e_local = lq*4+r (4 consecutive e), col = m = lr.
    #pragma unroll
    for (int mm = 0; mm < 2; ++mm)
        #pragma unroll
        for (int j = 0; j < 4; ++j) {
            f32x4 v = oacc[mm][j];
            v[0] *= inv[mm]; v[1] *= inv[mm]; v[2] *= inv[mm]; v[3] *= inv[mm];
            *(ushort4*)&o[(size_t)(b * SQ_ + q0 + w * 32 + mm * 16 + lr) * HD_ +
                          h * DK_ + j * 16 + lq * 4] = pack4(v);
        }
}

// ---------------------------------------------------------------------------
// Output projection: p[16384,256] = o[16384,512] @ Wp[256,512]^T (bf16 in,
// f32 out) with fused BN column partial sums. 128x64 tiles, K=512,
// register prefetch.
// ---------------------------------------------------------------------------
__global__ __launch_bounds__(256) void gemm_out(const unsigned short* __restrict__ A,
                                                const unsigned short* __restrict__ W,
                                                float* __restrict__ C,
                                                float* __restrict__ gsum,
                                                float* __restrict__ gsumsq) {
    __shared__ __align__(16) unsigned short As[128 * 72];
    __shared__ __align__(16) unsigned short Ws[64 * 72];
    const int tid = threadIdx.x;
    const int w = tid >> 6, l = tid & 63, lq = l >> 4, lr = l & 15;
    const int n0 = blockIdx.x * 64, m0 = blockIdx.y * 128;
    const int K = 512;

    const int arow = tid >> 1, aoff = (tid & 1) * 32;
    const int wrow = tid >> 2, woff = (tid & 3) * 16;

    f32x4 acc[2][4] = {};
    uint4 aR[4], wR[2];

    {
        const unsigned short* Ar = A + (size_t)(m0 + arow) * K + aoff;
        #pragma unroll
        for (int c = 0; c < 4; ++c) aR[c] = *(const uint4*)(Ar + c * 8);
        const unsigned short* Wr = W + (size_t)(n0 + wrow) * K + woff;
        #pragma unroll
        for (int c = 0; c < 2; ++c) wR[c] = *(const uint4*)(Wr + c * 8);
    }

    for (int k0 = 0; k0 < K; k0 += 64) {
        __syncthreads();
        #pragma unroll
        for (int c = 0; c < 4; ++c)
            *(uint4*)&As[arow * 72 + aoff + c * 8] = aR[c];
        #pragma unroll
        for (int c = 0; c < 2; ++c)
            *(uint4*)&Ws[wrow * 72 + woff + c * 8] = wR[c];

        if (k0 + 64 < K) {
            const unsigned short* Ar = A + (size_t)(m0 + arow) * K + k0 + 64 + aoff;
            #pragma unroll
            for (int c = 0; c < 4; ++c) aR[c] = *(const uint4*)(Ar + c * 8);
            const unsigned short* Wr = W + (size_t)(n0 + wrow) * K + k0 + 64 + woff;
            #pragma unroll
            for (int c = 0; c < 2; ++c) wR[c] = *(const uint4*)(Wr + c * 8);
        }
        __syncthreads();

        #pragma unroll
        for (int ks = 0; ks < 2; ++ks) {
            bf16x8 a0 = *(bf16x8*)&As[(w * 32 + lr) * 72 + ks * 32 + lq * 8];
            bf16x8 a1 = *(bf16x8*)&As[(w * 32 + 16 + lr) * 72 + ks * 32 + lq * 8];
            #pragma unroll
            for (int j = 0; j < 4; ++j) {
                bf16x8 bb = *(bf16x8*)&Ws[(j * 16 + lr) * 72 + ks * 32 + lq * 8];
                acc[0][j] = __builtin_amdgcn_mfma_f32_16x16x32_bf16(a0, bb, acc[0][j], 0, 0, 0);
                acc[1][j] = __builtin_amdgcn_mfma_f32_16x16x32_bf16(a1, bb, acc[1][j], 0, 0, 0);
            }
        }
    }

    float cs[4] = {}, cq[4] = {};
    #pragma unroll
    for (int m = 0; m < 2; ++m)
        #pragma unroll
        for (int j = 0; j < 4; ++j)
            #pragma unroll
            for (int r = 0; r < 4; ++r) {
                float v = acc[m][j][r];
                C[(size_t)(m0 + w * 32 + m * 16 + lq * 4 + r) * 256 + n0 + j * 16 + lr] = v;
                cs[j] += v;
                cq[j] += v * v;
            }
    #pragma unroll
    for (int j = 0; j < 4; ++j) {
        cs[j] += __shfl_xor(cs[j], 16); cs[j] += __shfl_xor(cs[j], 32);
        cq[j] += __shfl_xor(cq[j], 16); cq[j] += __shfl_xor(cq[j], 32);
    }
    __syncthreads();
    float* red = (float*)As;
    if (lq == 0) {
        #pragma unroll
        for (int j = 0; j < 4; ++j) {
            red[w * 128 + j * 16 + lr]      = cs[j];
            red[w * 128 + 64 + j * 16 + lr] = cq[j];
        }
    }
    __syncthreads();
    if (tid < 128) {
        int col = tid & 63, stat = tid >> 6;
        float t = red[stat * 64 + col] + red[128 + stat * 64 + col] +
                  red[256 + stat * 64 + col] + red[384 + stat * 64 + col];
        atomicAdd((stat ? gsumsq : gsum) + n0 + col, t);
    }
}

// ---------------------------------------------------------------------------
// Normalize + affine + LeakyReLU
// ---------------------------------------------------------------------------
__global__ __launch_bounds__(256) void bn_norm4(const float* __restrict__ p,
                                                const float* __restrict__ gsum,
                                                const float* __restrict__ gsumsq,
                                                const float* __restrict__ gamma,
                                                const float* __restrict__ beta,
                                                float* __restrict__ out) {
    int i = blockIdx.x * 256 + threadIdx.x;
    int c0 = (i * 4) & 255;
    const float invN = 1.0f / (float)NROWS;
    float4 pv = *(const float4*)(p + (size_t)i * 4);
    float vals[4] = {pv.x, pv.y, pv.z, pv.w};
    float res[4];
    #pragma unroll
    for (int k = 0; k < 4; ++k) {
        int c = c0 + k;
        float mean = gsum[c] * invN;
        float var  = gsumsq[c] * invN - mean * mean;
        float v = (vals[k] - mean) * rsqrtf(var + BN_EPS) * gamma[c] + beta[c];
        res[k] = v >= 0.f ? v : NEG_SLOPE * v;
    }
    float4 ov = {res[0], res[1], res[2], res[3]};
    *(float4*)(out + (size_t)i * 4) = ov;
}

// ---------------------------------------------------------------------------
// kernel_launch
// ---------------------------------------------------------------------------
extern "C" void kernel_launch(void* const* d_in, const int* in_sizes, int n_in,
                              void* d_out, int out_size, void* d_ws, size_t ws_size,
                              hipStream_t stream) {
    const float* x     = (const float*)d_in[0];
    const float* q     = (const float*)d_in[1];
    const float* Wq    = (const float*)d_in[2];
    const float* Wk    = (const float*)d_in[3];
    const float* Wv    = (const float*)d_in[4];
    const float* Wp    = (const float*)d_in[5];
    const float* gamma = (const float*)d_in[6];
    const float* beta  = (const float*)d_in[7];
    float* out = (float*)d_out;

    char* base = (char*)d_ws;
    unsigned short* Wqb  = (unsigned short*)(base + 0);          //  512x256 bf16
    unsigned short* Wkvb = (unsigned short*)(base + 262144);     // 1024x256 bf16
    unsigned short* Wpb  = (unsigned short*)(base + 786432);     //  256x512 bf16
    unsigned short* qh   = (unsigned short*)(base + 1048576);    // 16384x512 bf16
    unsigned short* khb  = (unsigned short*)(base + 17825792);   // 16384x512 bf16
    unsigned short* vTb  = (unsigned short*)(base + 34603008);   // [16,8,64,1024] bf16
    unsigned short* ob   = (unsigned short*)(base + 51380224);   // 16384x512 bf16
    float*          pbuf = (float*)        (base + 68157440);    // 16384x256 f32
    float*          stats= (float*)        (base + 84934656);    // 512 f32
    unsigned short* qbf  = (unsigned short*)(base + 84936704);   // 16384x256 bf16
    unsigned short* xbf  = (unsigned short*)(base + 93325312);   // 16384x256 bf16

    wcast<<<512, 256, 0, stream>>>(Wq, Wk, Wv, Wp, Wqb, Wkvb, Wpb, stats);
    qx_cast<<<8192, 256, 0, stream>>>(q, x, qbf, xbf);

    gemm_qkv3<<<dim3(12, 128), 256, 0, stream>>>(qbf, xbf, Wqb, Wkvb, qh, khb, vTb);

    attn_mfma7<<<dim3(8, 8, 16), 256, 0, stream>>>(qh, khb, vTb, ob);

    gemm_out<<<dim3(4, 128), 256, 0, stream>>>(ob, Wpb, pbuf, stats, stats + 256);

    bn_norm4<<<4096, 256, 0, stream>>>(pbuf, stats, stats + 256, gamma, beta, out);
}

// Round 11
// 268.362 us; speedup vs baseline: 1.0017x; 1.0017x over previous
//
#include <hip/hip_runtime.h>
#include <cstddef>

#define B_    16
#define SQ_   1024
#define SE_   1024
#define CIN_  256
#define DK_   64
#define H_    8
#define HD_   512
#define NROWS 16384
#define BN_EPS 1e-5f
#define NEG_SLOPE 0.01f

typedef __attribute__((ext_vector_type(8))) short bf16x8;
typedef __attribute__((ext_vector_type(4))) float f32x4;

__device__ __forceinline__ unsigned short f2bf(float f) {  // RNE
    unsigned int u = __float_as_uint(f);
    return (unsigned short)((u + 0x7FFFu + ((u >> 16) & 1u)) >> 16);
}

#if __has_builtin(__builtin_amdgcn_perm)
__device__ __forceinline__ unsigned int pack_trunc(float lo, float hi) {
    return __builtin_amdgcn_perm(__float_as_uint(hi), __float_as_uint(lo), 0x07060302u);
}
#else
__device__ __forceinline__ unsigned int pack_trunc(float lo, float hi) {
    return (__float_as_uint(lo) >> 16) | (__float_as_uint(hi) & 0xFFFF0000u);
}
#endif

#if __has_builtin(__builtin_amdgcn_exp2f)
#define EXP2F(x) __builtin_amdgcn_exp2f(x)
#else
#define EXP2F(x) exp2f(x)
#endif

__device__ __forceinline__ ushort4 pack4(f32x4 v) {
    ushort4 p;
    p.x = f2bf(v[0]); p.y = f2bf(v[1]);
    p.z = f2bf(v[2]); p.w = f2bf(v[3]);
    return p;
}

// ---------------------------------------------------------------------------
// Weight casts (one dispatch). Wq gets 0.125*log2(e) folded in.
// Blocks 0..1 also zero the BN stats accumulators.
// ---------------------------------------------------------------------------
__global__ __launch_bounds__(256) void wcast(const float* __restrict__ Wq,
                                             const float* __restrict__ Wk,
                                             const float* __restrict__ Wv,
                                             const float* __restrict__ Wp,
                                             unsigned short* __restrict__ dWq,
                                             unsigned short* __restrict__ dWkv,
                                             unsigned short* __restrict__ dWp,
                                             float* __restrict__ stats) {
    if (blockIdx.x < 2) stats[blockIdx.x * 256 + threadIdx.x] = 0.f;
    int i = blockIdx.x * 256 + threadIdx.x;
    int which = i >> 15, off = i & 32767;
    const float* s; unsigned short* d; float sc = 1.0f;
    if (which == 0)      { s = Wq; d = dWq; sc = 0.18033688011112042f; }
    else if (which == 1) { s = Wk; d = dWkv; }
    else if (which == 2) { s = Wv; d = dWkv + 131072; }
    else                 { s = Wp; d = dWp; }
    float4 v = *(const float4*)(s + (size_t)off * 4);
    ushort4 pk;
    pk.x = f2bf(v.x * sc); pk.y = f2bf(v.y * sc);
    pk.z = f2bf(v.z * sc); pk.w = f2bf(v.w * sc);
    *(ushort4*)(d + (size_t)off * 4) = pk;
}

// ---------------------------------------------------------------------------
// q / x fp32 -> bf16 pre-cast (memory-bound).
// ---------------------------------------------------------------------------
__global__ __launch_bounds__(256) void qx_cast(const float* __restrict__ q,
                                               const float* __restrict__ x,
                                               unsigned short* __restrict__ qbf,
                                               unsigned short* __restrict__ xbf) {
    int i = blockIdx.x * 256 + threadIdx.x;    // float4 index, 2*1048576 total
    const float* s = (i < 1048576) ? q : x;
    unsigned short* d = (i < 1048576) ? qbf : xbf;
    int off = i & 1048575;
    float4 v = *(const float4*)(s + (size_t)off * 4);
    ushort4 pk;
    pk.x = f2bf(v.x); pk.y = f2bf(v.y);
    pk.z = f2bf(v.z); pk.w = f2bf(v.w);
    *(ushort4*)(d + (size_t)off * 4) = pk;
}

// ---------------------------------------------------------------------------
// Fused Q+KV projection GEMM, 128x128 tile, BK=64, bf16 A, register
// prefetch. grid (12,128): bx<4 Q, 4..7 K, 8..11 V.
// Q/K: transposed compute mfma(W,A) -> acc regs run along n.
// V:   normal compute -> acc regs run along m (= t of the vT layout).
// Epilogue: stage the 128x128 bf16 C-tile in LDS (stride 136 shorts = 272 B
// -> every row 16B-aligned), then fully-coalesced 16B global stores
// (64 shorts = 8 x uint4 per thread; consecutive lanes -> consecutive addrs).
// ---------------------------------------------------------------------------
__global__ __launch_bounds__(256) void gemm_qkv4(const unsigned short* __restrict__ qbf,
                                                 const unsigned short* __restrict__ xbf,
                                                 const unsigned short* __restrict__ Wqb,
                                                 const unsigned short* __restrict__ Wkvb,
                                                 unsigned short* __restrict__ qh,
                                                 unsigned short* __restrict__ khb,
                                                 unsigned short* __restrict__ vTb) {
    __shared__ __align__(16) unsigned short smem[18432];    // 36 KB
    unsigned short* As = smem;                              // 128*72
    unsigned short* Ws = smem + 9216;                       // 128*72
    unsigned short* Cs = smem;                              // epilogue: 128*136

    const int tid = threadIdx.x;
    const int w = tid >> 6, l = tid & 63, lq = l >> 4, lr = l & 15;
    const int bx = blockIdx.x;
    const bool isQ = bx < 4;
    const bool isV = bx >= 8;
    const unsigned short* A = isQ ? qbf : xbf;
    const unsigned short* W = isQ ? Wqb : Wkvb;
    const int n0 = (isQ ? bx : bx - 4) * 128;
    const int m0 = blockIdx.y * 128;
    const int K = 256;

    const int srow = tid >> 1, soff = (tid & 1) * 32;   // 32 shorts/thread

    f32x4 acc[2][8] = {};
    uint4 aR[4], wR[4];

    {
        const unsigned short* Ar = A + (size_t)(m0 + srow) * K + soff;
        const unsigned short* Wr = W + (size_t)(n0 + srow) * K + soff;
        #pragma unroll
        for (int c = 0; c < 4; ++c) {
            aR[c] = *(const uint4*)(Ar + c * 8);
            wR[c] = *(const uint4*)(Wr + c * 8);
        }
    }

    for (int k0 = 0; k0 < K; k0 += 64) {
        __syncthreads();
        #pragma unroll
        for (int c = 0; c < 4; ++c) {
            *(uint4*)&As[srow * 72 + soff + c * 8] = aR[c];
            *(uint4*)&Ws[srow * 72 + soff + c * 8] = wR[c];
        }
        if (k0 + 64 < K) {
            const unsigned short* Ar = A + (size_t)(m0 + srow) * K + k0 + 64 + soff;
            const unsigned short* Wr = W + (size_t)(n0 + srow) * K + k0 + 64 + soff;
            #pragma unroll
            for (int c = 0; c < 4; ++c) {
                aR[c] = *(const uint4*)(Ar + c * 8);
                wR[c] = *(const uint4*)(Wr + c * 8);
            }
        }
        __syncthreads();

        if (!isV) {   // transposed compute: D[n][m]; reg r runs along n
            #pragma unroll
            for (int ks = 0; ks < 2; ++ks) {
                bf16x8 a0 = *(bf16x8*)&As[(w * 32 + lr) * 72 + ks * 32 + lq * 8];
                bf16x8 a1 = *(bf16x8*)&As[(w * 32 + 16 + lr) * 72 + ks * 32 + lq * 8];
                #pragma unroll
                for (int j = 0; j < 8; ++j) {
                    bf16x8 bb = *(bf16x8*)&Ws[(j * 16 + lr) * 72 + ks * 32 + lq * 8];
                    acc[0][j] = __builtin_amdgcn_mfma_f32_16x16x32_bf16(bb, a0, acc[0][j], 0, 0, 0);
                    acc[1][j] = __builtin_amdgcn_mfma_f32_16x16x32_bf16(bb, a1, acc[1][j], 0, 0, 0);
                }
            }
        } else {      // normal compute: D[m][n]; reg r runs along m
            #pragma unroll
            for (int ks = 0; ks < 2; ++ks) {
                bf16x8 a0 = *(bf16x8*)&As[(w * 32 + lr) * 72 + ks * 32 + lq * 8];
                bf16x8 a1 = *(bf16x8*)&As[(w * 32 + 16 + lr) * 72 + ks * 32 + lq * 8];
                #pragma unroll
                for (int j = 0; j < 8; ++j) {
                    bf16x8 bb = *(bf16x8*)&Ws[(j * 16 + lr) * 72 + ks * 32 + lq * 8];
                    acc[0][j] = __builtin_amdgcn_mfma_f32_16x16x32_bf16(a0, bb, acc[0][j], 0, 0, 0);
                    acc[1][j] = __builtin_amdgcn_mfma_f32_16x16x32_bf16(a1, bb, acc[1][j], 0, 0, 0);
                }
            }
        }
    }

    // ---- Epilogue: LDS transpose staging, then coalesced stores ----
    __syncthreads();   // done reading As/Ws; reuse as Cs
    if (!isV) {
        // acc[mf][j][r]: m = m0 + w*32 + mf*16 + lr, n = n0 + j*16 + lq*4 + r
        // Stage as Cs[m_local][n_local] (4 consecutive n per write):
        #pragma unroll
        for (int mf = 0; mf < 2; ++mf)
            #pragma unroll
            for (int j = 0; j < 8; ++j)
                *(ushort4*)&Cs[(w * 32 + mf * 16 + lr) * 136 + j * 16 + lq * 4] =
                    pack4(acc[mf][j]);
        __syncthreads();
        // Coalesced out: thread -> row tid>>1, half (tid&1)*64, 64 shorts
        unsigned short* C = isQ ? qh : khb;
        const int r = tid >> 1, half = (tid & 1) * 64;
        unsigned short* dst = C + (size_t)(m0 + r) * 512 + n0 + half;
        const unsigned short* src = Cs + r * 136 + half;
        #pragma unroll
        for (int c = 0; c < 8; ++c)
            *(uint4*)(dst + c * 8) = *(const uint4*)(src + c * 8);
    } else {
        // acc[mf][j][r]: m = m0 + w*32 + mf*16 + lq*4 + r, n = n0 + j*16 + lr
        // Stage as Cs[n_local][m_local] (vT wants [e][t], t = m; 4 consecutive t):
        #pragma unroll
        for (int mf = 0; mf < 2; ++mf)
            #pragma unroll
            for (int j = 0; j < 8; ++j)
                *(ushort4*)&Cs[(j * 16 + lr) * 136 + w * 32 + mf * 16 + lq * 4] =
                    pack4(acc[mf][j]);
        __syncthreads();
        const int n = tid >> 1, half = (tid & 1) * 64;
        const int colv = n0 - 512 + n;
        const int hh = colv >> 6, e = colv & 63;
        const int bb = m0 >> 10, t0 = m0 & 1023;
        unsigned short* dst = vTb + (size_t)((bb * 8 + hh) * 64 + e) * 1024 + t0 + half;
        const unsigned short* src = Cs + n * 136 + half;
        #pragma unroll
        for (int c = 0; c < 8; ++c)
            *(uint4*)(dst + c * 8) = *(const uint4*)(src + c * 8);
    }
}

// ---------------------------------------------------------------------------
// MFMA flash attention v7: R3 staging skeleton (LDS K/V, two barriers) +
// S^T mfma(K,Q) + packed-b64 P writes + transposed PV mfma(V,P) -> packed
// ushort4 o-stores, scalar per-lane inv (no broadcast shuffles).
// ---------------------------------------------------------------------------
__global__ __launch_bounds__(256) void attn_mfma7(const unsigned short* __restrict__ qh,
                                                  const unsigned short* __restrict__ kh,
                                                  const unsigned short* __restrict__ vT,
                                                  unsigned short* __restrict__ o) {
    __shared__ __align__(16) unsigned short Ks[64 * 72];      // [key][d]
    __shared__ __align__(16) unsigned short Vs[64 * 72];      // [e][t]
    __shared__ __align__(16) unsigned short Ps[4][32 * 72];   // per-wave P [m][t]

    const int tid = threadIdx.x;
    const int w = tid >> 6, l = tid & 63, lq = l >> 4, lr = l & 15;
    const int q0 = blockIdx.x * 128, h = blockIdx.y, b = blockIdx.z;

    bf16x8 qf[2][2];
    #pragma unroll
    for (int m = 0; m < 2; ++m) {
        const unsigned short* qr =
            qh + (size_t)(b * SQ_ + q0 + w * 32 + m * 16 + lr) * HD_ + h * DK_;
        qf[m][0] = *(const bf16x8*)(qr + lq * 8);
        qf[m][1] = *(const bf16x8*)(qr + 32 + lq * 8);
    }

    const unsigned short* kb = kh + (size_t)(b * SE_) * HD_ + h * DK_;
    const unsigned short* vb = vT + (size_t)((b * 8 + h) * 64) * 1024;

    const int se = tid >> 3;        // 0..31
    const int sc = (tid & 7) * 8;

    float l_i[2] = {};              // per-lane partial row-sum; m = mm*16 + lr
    f32x4 oacc[2][4] = {};          // [mm][e-strip j]; D[e][m]
    unsigned short* Pw = Ps[w];

    for (int t0 = 0; t0 < SE_; t0 += 64) {
        __syncthreads();
        #pragma unroll
        for (int ps = 0; ps < 2; ++ps) {
            int rr = se + ps * 32;
            *(uint4*)&Ks[rr * 72 + sc] = *(const uint4*)(kb + (size_t)(t0 + rr) * HD_ + sc);
            *(uint4*)&Vs[rr * 72 + sc] = *(const uint4*)(vb + (size_t)rr * 1024 + t0 + sc);
        }
        __syncthreads();

        // S^T tiles: sT[tt][mm]; C row = t (lq*4+r), col = m (lr)
        f32x4 sT[4][2] = {};
        #pragma unroll
        for (int ks = 0; ks < 2; ++ks)
            #pragma unroll
            for (int tt = 0; tt < 4; ++tt) {
                bf16x8 kf = *(bf16x8*)&Ks[(tt * 16 + lr) * 72 + ks * 32 + lq * 8];
                sT[tt][0] = __builtin_amdgcn_mfma_f32_16x16x32_bf16(kf, qf[0][ks], sT[tt][0], 0, 0, 0);
                sT[tt][1] = __builtin_amdgcn_mfma_f32_16x16x32_bf16(kf, qf[1][ks], sT[tt][1], 0, 0, 0);
            }

        // exp2 + lane-local l accum + packed b64 P write (4 consecutive t)
        #pragma unroll
        for (int mm = 0; mm < 2; ++mm)
            #pragma unroll
            for (int tt = 0; tt < 4; ++tt) {
                float e0 = EXP2F(sT[tt][mm][0]);
                float e1 = EXP2F(sT[tt][mm][1]);
                float e2 = EXP2F(sT[tt][mm][2]);
                float e3 = EXP2F(sT[tt][mm][3]);
                l_i[mm] += (e0 + e1) + (e2 + e3);
                uint2 pk;
                pk.x = pack_trunc(e0, e1);
                pk.y = pack_trunc(e2, e3);
                *(uint2*)&Pw[(mm * 16 + lr) * 72 + tt * 16 + lq * 4] = pk;
            }
        asm volatile("s_waitcnt lgkmcnt(0)" ::: "memory");   // wave-local round trip

        // PV transposed: oacc[mm][j] = V_strip_j . P_mm^T -> D[e][m]
        #pragma unroll
        for (int ks = 0; ks < 2; ++ks) {
            bf16x8 pf0 = *(bf16x8*)&Pw[(lr) * 72 + ks * 32 + lq * 8];
            bf16x8 pf1 = *(bf16x8*)&Pw[(16 + lr) * 72 + ks * 32 + lq * 8];
            #pragma unroll
            for (int j = 0; j < 4; ++j) {
                bf16x8 vf = *(bf16x8*)&Vs[(j * 16 + lr) * 72 + ks * 32 + lq * 8];
                oacc[0][j] = __builtin_amdgcn_mfma_f32_16x16x32_bf16(vf, pf0, oacc[0][j], 0, 0, 0);
                oacc[1][j] = __builtin_amdgcn_mfma_f32_16x16x32_bf16(vf, pf1, oacc[1][j], 0, 0, 0);
            }
        }
    }

    float inv[2];
    #pragma unroll
    for (int mm = 0; mm < 2; ++mm) {
        float t = l_i[mm];
        t += __shfl_xor(t, 16);
        t += __shfl_xor(t, 32);
        inv[mm] = 1.0f / t;
    }

    #pragma unroll
    for (int mm = 0; mm < 2; ++mm)
        #pragma unroll
        for (int j = 0; j < 4; ++j) {
            f32x4 v = oacc[mm][j];
            v[0] *= inv[mm]; v[1] *= inv[mm]; v[2] *= inv[mm]; v[3] *= inv[mm];
            *(ushort4*)&o[(size_t)(b * SQ_ + q0 + w * 32 + mm * 16 + lr) * HD_ +
                          h * DK_ + j * 16 + lq * 4] = pack4(v);
        }
}

// ---------------------------------------------------------------------------
// Output projection: p = o @ Wp^T (bf16 in, f32 out) + fused BN partials.
// 128x64 tiles, K=512, register prefetch.
// ---------------------------------------------------------------------------
__global__ __launch_bounds__(256) void gemm_out(const unsigned short* __restrict__ A,
                                                const unsigned short* __restrict__ W,
                                                float* __restrict__ C,
                                                float* __restrict__ gsum,
                                                float* __restrict__ gsumsq) {
    __shared__ __align__(16) unsigned short As[128 * 72];
    __shared__ __align__(16) unsigned short Ws[64 * 72];
    const int tid = threadIdx.x;
    const int w = tid >> 6, l = tid & 63, lq = l >> 4, lr = l & 15;
    const int n0 = blockIdx.x * 64, m0 = blockIdx.y * 128;
    const int K = 512;

    const int arow = tid >> 1, aoff = (tid & 1) * 32;
    const int wrow = tid >> 2, woff = (tid & 3) * 16;

    f32x4 acc[2][4] = {};
    uint4 aR[4], wR[2];

    {
        const unsigned short* Ar = A + (size_t)(m0 + arow) * K + aoff;
        #pragma unroll
        for (int c = 0; c < 4; ++c) aR[c] = *(const uint4*)(Ar + c * 8);
        const unsigned short* Wr = W + (size_t)(n0 + wrow) * K + woff;
        #pragma unroll
        for (int c = 0; c < 2; ++c) wR[c] = *(const uint4*)(Wr + c * 8);
    }

    for (int k0 = 0; k0 < K; k0 += 64) {
        __syncthreads();
        #pragma unroll
        for (int c = 0; c < 4; ++c)
            *(uint4*)&As[arow * 72 + aoff + c * 8] = aR[c];
        #pragma unroll
        for (int c = 0; c < 2; ++c)
            *(uint4*)&Ws[wrow * 72 + woff + c * 8] = wR[c];

        if (k0 + 64 < K) {
            const unsigned short* Ar = A + (size_t)(m0 + arow) * K + k0 + 64 + aoff;
            #pragma unroll
            for (int c = 0; c < 4; ++c) aR[c] = *(const uint4*)(Ar + c * 8);
            const unsigned short* Wr = W + (size_t)(n0 + wrow) * K + k0 + 64 + woff;
            #pragma unroll
            for (int c = 0; c < 2; ++c) wR[c] = *(const uint4*)(Wr + c * 8);
        }
        __syncthreads();

        #pragma unroll
        for (int ks = 0; ks < 2; ++ks) {
            bf16x8 a0 = *(bf16x8*)&As[(w * 32 + lr) * 72 + ks * 32 + lq * 8];
            bf16x8 a1 = *(bf16x8*)&As[(w * 32 + 16 + lr) * 72 + ks * 32 + lq * 8];
            #pragma unroll
            for (int j = 0; j < 4; ++j) {
                bf16x8 bb = *(bf16x8*)&Ws[(j * 16 + lr) * 72 + ks * 32 + lq * 8];
                acc[0][j] = __builtin_amdgcn_mfma_f32_16x16x32_bf16(a0, bb, acc[0][j], 0, 0, 0);
                acc[1][j] = __builtin_amdgcn_mfma_f32_16x16x32_bf16(a1, bb, acc[1][j], 0, 0, 0);
            }
        }
    }

    float cs[4] = {}, cq[4] = {};
    #pragma unroll
    for (int m = 0; m < 2; ++m)
        #pragma unroll
        for (int j = 0; j < 4; ++j)
            #pragma unroll
            for (int r = 0; r < 4; ++r) {
                float v = acc[m][j][r];
                C[(size_t)(m0 + w * 32 + m * 16 + lq * 4 + r) * 256 + n0 + j * 16 + lr] = v;
                cs[j] += v;
                cq[j] += v * v;
            }
    #pragma unroll
    for (int j = 0; j < 4; ++j) {
        cs[j] += __shfl_xor(cs[j], 16); cs[j] += __shfl_xor(cs[j], 32);
        cq[j] += __shfl_xor(cq[j], 16); cq[j] += __shfl_xor(cq[j], 32);
    }
    __syncthreads();
    float* red = (float*)As;
    if (lq == 0) {
        #pragma unroll
        for (int j = 0; j < 4; ++j) {
            red[w * 128 + j * 16 + lr]      = cs[j];
            red[w * 128 + 64 + j * 16 + lr] = cq[j];
        }
    }
    __syncthreads();
    if (tid < 128) {
        int col = tid & 63, stat = tid >> 6;
        float t = red[stat * 64 + col] + red[128 + stat * 64 + col] +
                  red[256 + stat * 64 + col] + red[384 + stat * 64 + col];
        atomicAdd((stat ? gsumsq : gsum) + n0 + col, t);
    }
}

// ---------------------------------------------------------------------------
// Normalize + affine + LeakyReLU
// ---------------------------------------------------------------------------
__global__ __launch_bounds__(256) void bn_norm4(const float* __restrict__ p,
                                                const float* __restrict__ gsum,
                                                const float* __restrict__ gsumsq,
                                                const float* __restrict__ gamma,
                                                const float* __restrict__ beta,
                                                float* __restrict__ out) {
    int i = blockIdx.x * 256 + threadIdx.x;
    int c0 = (i * 4) & 255;
    const float invN = 1.0f / (float)NROWS;
    float4 pv = *(const float4*)(p + (size_t)i * 4);
    float vals[4] = {pv.x, pv.y, pv.z, pv.w};
    float res[4];
    #pragma unroll
    for (int k = 0; k < 4; ++k) {
        int c = c0 + k;
        float mean = gsum[c] * invN;
        float var  = gsumsq[c] * invN - mean * mean;
        float v = (vals[k] - mean) * rsqrtf(var + BN_EPS) * gamma[c] + beta[c];
        res[k] = v >= 0.f ? v : NEG_SLOPE * v;
    }
    float4 ov = {res[0], res[1], res[2], res[3]};
    *(float4*)(out + (size_t)i * 4) = ov;
}

// ---------------------------------------------------------------------------
// kernel_launch
// ---------------------------------------------------------------------------
extern "C" void kernel_launch(void* const* d_in, const int* in_sizes, int n_in,
                              void* d_out, int out_size, void* d_ws, size_t ws_size,
                              hipStream_t stream) {
    const float* x     = (const float*)d_in[0];
    const float* q     = (const float*)d_in[1];
    const float* Wq    = (const float*)d_in[2];
    const float* Wk    = (const float*)d_in[3];
    const float* Wv    = (const float*)d_in[4];
    const float* Wp    = (const float*)d_in[5];
    const float* gamma = (const float*)d_in[6];
    const float* beta  = (const float*)d_in[7];
    float* out = (float*)d_out;

    char* base = (char*)d_ws;
    unsigned short* Wqb  = (unsigned short*)(base + 0);          //  512x256 bf16
    unsigned short* Wkvb = (unsigned short*)(base + 262144);     // 1024x256 bf16
    unsigned short* Wpb  = (unsigned short*)(base + 786432);     //  256x512 bf16
    unsigned short* qh   = (unsigned short*)(base + 1048576);    // 16384x512 bf16
    unsigned short* khb  = (unsigned short*)(base + 17825792);   // 16384x512 bf16
    unsigned short* vTb  = (unsigned short*)(base + 34603008);   // [16,8,64,1024] bf16
    unsigned short* ob   = (unsigned short*)(base + 51380224);   // 16384x512 bf16
    float*          pbuf = (float*)        (base + 68157440);    // 16384x256 f32
    float*          stats= (float*)        (base + 84934656);    // 512 f32
    unsigned short* qbf  = (unsigned short*)(base + 84936704);   // 16384x256 bf16
    unsigned short* xbf  = (unsigned short*)(base + 93325312);   // 16384x256 bf16

    wcast<<<512, 256, 0, stream>>>(Wq, Wk, Wv, Wp, Wqb, Wkvb, Wpb, stats);
    qx_cast<<<8192, 256, 0, stream>>>(q, x, qbf, xbf);

    gemm_qkv4<<<dim3(12, 128), 256, 0, stream>>>(qbf, xbf, Wqb, Wkvb, qh, khb, vTb);

    attn_mfma7<<<dim3(8, 8, 16), 256, 0, stream>>>(qh, khb, vTb, ob);

    gemm_out<<<dim3(4, 128), 256, 0, stream>>>(ob, Wpb, pbuf, stats, stats + 256);

    bn_norm4<<<4096, 256, 0, stream>>>(pbuf, stats, stats + 256, gamma, beta, out);
}

// Round 12
// 261.192 us; speedup vs baseline: 1.0292x; 1.0275x over previous
//
#include <hip/hip_runtime.h>
#include <cstddef>

#define B_    16
#define SQ_   1024
#define SE_   1024
#define CIN_  256
#define DK_   64
#define H_    8
#define HD_   512
#define NROWS 16384
#define BN_EPS 1e-5f
#define NEG_SLOPE 0.01f

typedef __attribute__((ext_vector_type(8))) short bf16x8;
typedef __attribute__((ext_vector_type(4))) float f32x4;

__device__ __forceinline__ unsigned short f2bf(float f) {  // RNE
    unsigned int u = __float_as_uint(f);
    return (unsigned short)((u + 0x7FFFu + ((u >> 16) & 1u)) >> 16);
}

#if __has_builtin(__builtin_amdgcn_perm)
__device__ __forceinline__ unsigned int pack_trunc(float lo, float hi) {
    return __builtin_amdgcn_perm(__float_as_uint(hi), __float_as_uint(lo), 0x07060302u);
}
#else
__device__ __forceinline__ unsigned int pack_trunc(float lo, float hi) {
    return (__float_as_uint(lo) >> 16) | (__float_as_uint(hi) & 0xFFFF0000u);
}
#endif

#if __has_builtin(__builtin_amdgcn_exp2f)
#define EXP2F(x) __builtin_amdgcn_exp2f(x)
#else
#define EXP2F(x) exp2f(x)
#endif

__device__ __forceinline__ ushort4 pack4(f32x4 v) {
    ushort4 p;
    p.x = f2bf(v[0]); p.y = f2bf(v[1]);
    p.z = f2bf(v[2]); p.w = f2bf(v[3]);
    return p;
}

// ---------------------------------------------------------------------------
// Weight casts (one dispatch). Wq gets 0.125*log2(e) folded in.
// Blocks 0..1 also zero the BN stats accumulators.
// ---------------------------------------------------------------------------
__global__ __launch_bounds__(256) void wcast(const float* __restrict__ Wq,
                                             const float* __restrict__ Wk,
                                             const float* __restrict__ Wv,
                                             const float* __restrict__ Wp,
                                             unsigned short* __restrict__ dWq,
                                             unsigned short* __restrict__ dWkv,
                                             unsigned short* __restrict__ dWp,
                                             float* __restrict__ stats) {
    if (blockIdx.x < 2) stats[blockIdx.x * 256 + threadIdx.x] = 0.f;
    int i = blockIdx.x * 256 + threadIdx.x;
    int which = i >> 15, off = i & 32767;
    const float* s; unsigned short* d; float sc = 1.0f;
    if (which == 0)      { s = Wq; d = dWq; sc = 0.18033688011112042f; }
    else if (which == 1) { s = Wk; d = dWkv; }
    else if (which == 2) { s = Wv; d = dWkv + 131072; }
    else                 { s = Wp; d = dWp; }
    float4 v = *(const float4*)(s + (size_t)off * 4);
    ushort4 pk;
    pk.x = f2bf(v.x * sc); pk.y = f2bf(v.y * sc);
    pk.z = f2bf(v.z * sc); pk.w = f2bf(v.w * sc);
    *(ushort4*)(d + (size_t)off * 4) = pk;
}

// ---------------------------------------------------------------------------
// q / x fp32 -> bf16 pre-cast (memory-bound).
// ---------------------------------------------------------------------------
__global__ __launch_bounds__(256) void qx_cast(const float* __restrict__ q,
                                               const float* __restrict__ x,
                                               unsigned short* __restrict__ qbf,
                                               unsigned short* __restrict__ xbf) {
    int i = blockIdx.x * 256 + threadIdx.x;    // float4 index, 2*1048576 total
    const float* s = (i < 1048576) ? q : x;
    unsigned short* d = (i < 1048576) ? qbf : xbf;
    int off = i & 1048575;
    float4 v = *(const float4*)(s + (size_t)off * 4);
    ushort4 pk;
    pk.x = f2bf(v.x); pk.y = f2bf(v.y);
    pk.z = f2bf(v.z); pk.w = f2bf(v.w);
    *(ushort4*)(d + (size_t)off * 4) = pk;
}

// ---------------------------------------------------------------------------
// Fused Q+KV projection GEMM, 128x128 tile, BK=64, bf16 A, register
// prefetch. grid (12,128): bx<4 Q, 4..7 K, 8..11 V.
// Q/K: transposed compute mfma(W,A); V: normal compute (vT layout).
// Epilogue: stage C-tile in LDS (stride 144 shorts: 16B-aligned rows,
// exactly fills the 36KB union), then FULL-LINE coalesced stores: per store
// instruction, each 16-lane group covers one contiguous 256B row strip ->
// the wave writes 16 complete 64B lines, zero partial-line writebacks.
// (R11 lesson: L2 does NOT merge partial-line writes across instructions —
//  210 MB WRITE for 50 MB payload with 16B/lane/line stores.)
// ---------------------------------------------------------------------------
__global__ __launch_bounds__(256) void gemm_qkv5(const unsigned short* __restrict__ qbf,
                                                 const unsigned short* __restrict__ xbf,
                                                 const unsigned short* __restrict__ Wqb,
                                                 const unsigned short* __restrict__ Wkvb,
                                                 unsigned short* __restrict__ qh,
                                                 unsigned short* __restrict__ khb,
                                                 unsigned short* __restrict__ vTb) {
    __shared__ __align__(16) unsigned short smem[18432];    // 36 KB
    unsigned short* As = smem;                              // 128*72
    unsigned short* Ws = smem + 9216;                       // 128*72
    unsigned short* Cs = smem;                              // epilogue: 128*144

    const int tid = threadIdx.x;
    const int w = tid >> 6, l = tid & 63, lq = l >> 4, lr = l & 15;
    const int bx = blockIdx.x;
    const bool isQ = bx < 4;
    const bool isV = bx >= 8;
    const unsigned short* A = isQ ? qbf : xbf;
    const unsigned short* W = isQ ? Wqb : Wkvb;
    const int n0 = (isQ ? bx : bx - 4) * 128;
    const int m0 = blockIdx.y * 128;
    const int K = 256;

    const int srow = tid >> 1, soff = (tid & 1) * 32;   // 32 shorts/thread

    f32x4 acc[2][8] = {};
    uint4 aR[4], wR[4];

    {
        const unsigned short* Ar = A + (size_t)(m0 + srow) * K + soff;
        const unsigned short* Wr = W + (size_t)(n0 + srow) * K + soff;
        #pragma unroll
        for (int c = 0; c < 4; ++c) {
            aR[c] = *(const uint4*)(Ar + c * 8);
            wR[c] = *(const uint4*)(Wr + c * 8);
        }
    }

    for (int k0 = 0; k0 < K; k0 += 64) {
        __syncthreads();
        #pragma unroll
        for (int c = 0; c < 4; ++c) {
            *(uint4*)&As[srow * 72 + soff + c * 8] = aR[c];
            *(uint4*)&Ws[srow * 72 + soff + c * 8] = wR[c];
        }
        if (k0 + 64 < K) {
            const unsigned short* Ar = A + (size_t)(m0 + srow) * K + k0 + 64 + soff;
            const unsigned short* Wr = W + (size_t)(n0 + srow) * K + k0 + 64 + soff;
            #pragma unroll
            for (int c = 0; c < 4; ++c) {
                aR[c] = *(const uint4*)(Ar + c * 8);
                wR[c] = *(const uint4*)(Wr + c * 8);
            }
        }
        __syncthreads();

        if (!isV) {   // transposed compute: D[n][m]; reg r runs along n
            #pragma unroll
            for (int ks = 0; ks < 2; ++ks) {
                bf16x8 a0 = *(bf16x8*)&As[(w * 32 + lr) * 72 + ks * 32 + lq * 8];
                bf16x8 a1 = *(bf16x8*)&As[(w * 32 + 16 + lr) * 72 + ks * 32 + lq * 8];
                #pragma unroll
                for (int j = 0; j < 8; ++j) {
                    bf16x8 bb = *(bf16x8*)&Ws[(j * 16 + lr) * 72 + ks * 32 + lq * 8];
                    acc[0][j] = __builtin_amdgcn_mfma_f32_16x16x32_bf16(bb, a0, acc[0][j], 0, 0, 0);
                    acc[1][j] = __builtin_amdgcn_mfma_f32_16x16x32_bf16(bb, a1, acc[1][j], 0, 0, 0);
                }
            }
        } else {      // normal compute: D[m][n]; reg r runs along m
            #pragma unroll
            for (int ks = 0; ks < 2; ++ks) {
                bf16x8 a0 = *(bf16x8*)&As[(w * 32 + lr) * 72 + ks * 32 + lq * 8];
                bf16x8 a1 = *(bf16x8*)&As[(w * 32 + 16 + lr) * 72 + ks * 32 + lq * 8];
                #pragma unroll
                for (int j = 0; j < 8; ++j) {
                    bf16x8 bb = *(bf16x8*)&Ws[(j * 16 + lr) * 72 + ks * 32 + lq * 8];
                    acc[0][j] = __builtin_amdgcn_mfma_f32_16x16x32_bf16(a0, bb, acc[0][j], 0, 0, 0);
                    acc[1][j] = __builtin_amdgcn_mfma_f32_16x16x32_bf16(a1, bb, acc[1][j], 0, 0, 0);
                }
            }
        }
    }

    // ---- Epilogue: LDS staging, then full-line coalesced stores ----
    __syncthreads();   // done reading As/Ws; reuse as Cs
    const int c16 = tid & 15;      // 16B chunk within a 256B row strip
    const int rb  = tid >> 4;      // 0..15
    if (!isV) {
        // acc[mf][j][r]: m = m0 + w*32 + mf*16 + lr, n = n0 + j*16 + lq*4 + r
        // Stage as Cs[m_local][n_local]:
        #pragma unroll
        for (int mf = 0; mf < 2; ++mf)
            #pragma unroll
            for (int j = 0; j < 8; ++j)
                *(ushort4*)&Cs[(w * 32 + mf * 16 + lr) * 144 + j * 16 + lq * 4] =
                    pack4(acc[mf][j]);
        __syncthreads();
        unsigned short* C = isQ ? qh : khb;
        #pragma unroll
        for (int it = 0; it < 8; ++it) {
            int r = it * 16 + rb;
            *(uint4*)(C + (size_t)(m0 + r) * 512 + n0 + c16 * 8) =
                *(const uint4*)(Cs + r * 144 + c16 * 8);
        }
    } else {
        // acc[mf][j][r]: m = m0 + w*32 + mf*16 + lq*4 + r, n = n0 + j*16 + lr
        // Stage as Cs[n_local][m_local] (vT wants [e][t], t = m):
        #pragma unroll
        for (int mf = 0; mf < 2; ++mf)
            #pragma unroll
            for (int j = 0; j < 8; ++j)
                *(ushort4*)&Cs[(j * 16 + lr) * 144 + w * 32 + mf * 16 + lq * 4] =
                    pack4(acc[mf][j]);
        __syncthreads();
        const int bb = m0 >> 10, t0 = m0 & 1023;
        #pragma unroll
        for (int it = 0; it < 8; ++it) {
            int el = it * 16 + rb;
            int colv = n0 - 512 + el;
            int hh = colv >> 6, e = colv & 63;
            *(uint4*)(vTb + (size_t)((bb * 8 + hh) * 64 + e) * 1024 + t0 + c16 * 8) =
                *(const uint4*)(Cs + el * 144 + c16 * 8);
        }
    }
}

// ---------------------------------------------------------------------------
// MFMA flash attention v7: R3 staging skeleton (LDS K/V, two barriers) +
// S^T mfma(K,Q) + packed-b64 P writes + transposed PV mfma(V,P) -> packed
// ushort4 o-stores, scalar per-lane inv (no broadcast shuffles).
// ---------------------------------------------------------------------------
__global__ __launch_bounds__(256) void attn_mfma7(const unsigned short* __restrict__ qh,
                                                  const unsigned short* __restrict__ kh,
                                                  const unsigned short* __restrict__ vT,
                                                  unsigned short* __restrict__ o) {
    __shared__ __align__(16) unsigned short Ks[64 * 72];      // [key][d]
    __shared__ __align__(16) unsigned short Vs[64 * 72];      // [e][t]
    __shared__ __align__(16) unsigned short Ps[4][32 * 72];   // per-wave P [m][t]

    const int tid = threadIdx.x;
    const int w = tid >> 6, l = tid & 63, lq = l >> 4, lr = l & 15;
    const int q0 = blockIdx.x * 128, h = blockIdx.y, b = blockIdx.z;

    bf16x8 qf[2][2];
    #pragma unroll
    for (int m = 0; m < 2; ++m) {
        const unsigned short* qr =
            qh + (size_t)(b * SQ_ + q0 + w * 32 + m * 16 + lr) * HD_ + h * DK_;
        qf[m][0] = *(const bf16x8*)(qr + lq * 8);
        qf[m][1] = *(const bf16x8*)(qr + 32 + lq * 8);
    }

    const unsigned short* kb = kh + (size_t)(b * SE_) * HD_ + h * DK_;
    const unsigned short* vb = vT + (size_t)((b * 8 + h) * 64) * 1024;

    const int se = tid >> 3;        // 0..31
    const int sc = (tid & 7) * 8;

    float l_i[2] = {};              // per-lane partial row-sum; m = mm*16 + lr
    f32x4 oacc[2][4] = {};          // [mm][e-strip j]; D[e][m]
    unsigned short* Pw = Ps[w];

    for (int t0 = 0; t0 < SE_; t0 += 64) {
        __syncthreads();
        #pragma unroll
        for (int ps = 0; ps < 2; ++ps) {
            int rr = se + ps * 32;
            *(uint4*)&Ks[rr * 72 + sc] = *(const uint4*)(kb + (size_t)(t0 + rr) * HD_ + sc);
            *(uint4*)&Vs[rr * 72 + sc] = *(const uint4*)(vb + (size_t)rr * 1024 + t0 + sc);
        }
        __syncthreads();

        // S^T tiles: sT[tt][mm]; C row = t (lq*4+r), col = m (lr)
        f32x4 sT[4][2] = {};
        #pragma unroll
        for (int ks = 0; ks < 2; ++ks)
            #pragma unroll
            for (int tt = 0; tt < 4; ++tt) {
                bf16x8 kf = *(bf16x8*)&Ks[(tt * 16 + lr) * 72 + ks * 32 + lq * 8];
                sT[tt][0] = __builtin_amdgcn_mfma_f32_16x16x32_bf16(kf, qf[0][ks], sT[tt][0], 0, 0, 0);
                sT[tt][1] = __builtin_amdgcn_mfma_f32_16x16x32_bf16(kf, qf[1][ks], sT[tt][1], 0, 0, 0);
            }

        // exp2 + lane-local l accum + packed b64 P write (4 consecutive t)
        #pragma unroll
        for (int mm = 0; mm < 2; ++mm)
            #pragma unroll
            for (int tt = 0; tt < 4; ++tt) {
                float e0 = EXP2F(sT[tt][mm][0]);
                float e1 = EXP2F(sT[tt][mm][1]);
                float e2 = EXP2F(sT[tt][mm][2]);
                float e3 = EXP2F(sT[tt][mm][3]);
                l_i[mm] += (e0 + e1) + (e2 + e3);
                uint2 pk;
                pk.x = pack_trunc(e0, e1);
                pk.y = pack_trunc(e2, e3);
                *(uint2*)&Pw[(mm * 16 + lr) * 72 + tt * 16 + lq * 4] = pk;
            }
        asm volatile("s_waitcnt lgkmcnt(0)" ::: "memory");   // wave-local round trip

        // PV transposed: oacc[mm][j] = V_strip_j . P_mm^T -> D[e][m]
        #pragma unroll
        for (int ks = 0; ks < 2; ++ks) {
            bf16x8 pf0 = *(bf16x8*)&Pw[(lr) * 72 + ks * 32 + lq * 8];
            bf16x8 pf1 = *(bf16x8*)&Pw[(16 + lr) * 72 + ks * 32 + lq * 8];
            #pragma unroll
            for (int j = 0; j < 4; ++j) {
                bf16x8 vf = *(bf16x8*)&Vs[(j * 16 + lr) * 72 + ks * 32 + lq * 8];
                oacc[0][j] = __builtin_amdgcn_mfma_f32_16x16x32_bf16(vf, pf0, oacc[0][j], 0, 0, 0);
                oacc[1][j] = __builtin_amdgcn_mfma_f32_16x16x32_bf16(vf, pf1, oacc[1][j], 0, 0, 0);
            }
        }
    }

    float inv[2];
    #pragma unroll
    for (int mm = 0; mm < 2; ++mm) {
        float t = l_i[mm];
        t += __shfl_xor(t, 16);
        t += __shfl_xor(t, 32);
        inv[mm] = 1.0f / t;
    }

    #pragma unroll
    for (int mm = 0; mm < 2; ++mm)
        #pragma unroll
        for (int j = 0; j < 4; ++j) {
            f32x4 v = oacc[mm][j];
            v[0] *= inv[mm]; v[1] *= inv[mm]; v[2] *= inv[mm]; v[3] *= inv[mm];
            *(ushort4*)&o[(size_t)(b * SQ_ + q0 + w * 32 + mm * 16 + lr) * HD_ +
                          h * DK_ + j * 16 + lq * 4] = pack4(v);
        }
}

// ---------------------------------------------------------------------------
// Output projection: p = o @ Wp^T (bf16 in, f32 out) + fused BN partials.
// 128x64 tiles, K=512, register prefetch.
// ---------------------------------------------------------------------------
__global__ __launch_bounds__(256) void gemm_out(const unsigned short* __restrict__ A,
                                                const unsigned short* __restrict__ W,
                                                float* __restrict__ C,
                                                float* __restrict__ gsum,
                                                float* __restrict__ gsumsq) {
    __shared__ __align__(16) unsigned short As[128 * 72];
    __shared__ __align__(16) unsigned short Ws[64 * 72];
    const int tid = threadIdx.x;
    const int w = tid >> 6, l = tid & 63, lq = l >> 4, lr = l & 15;
    const int n0 = blockIdx.x * 64, m0 = blockIdx.y * 128;
    const int K = 512;

    const int arow = tid >> 1, aoff = (tid & 1) * 32;
    const int wrow = tid >> 2, woff = (tid & 3) * 16;

    f32x4 acc[2][4] = {};
    uint4 aR[4], wR[2];

    {
        const unsigned short* Ar = A + (size_t)(m0 + arow) * K + aoff;
        #pragma unroll
        for (int c = 0; c < 4; ++c) aR[c] = *(const uint4*)(Ar + c * 8);
        const unsigned short* Wr = W + (size_t)(n0 + wrow) * K + woff;
        #pragma unroll
        for (int c = 0; c < 2; ++c) wR[c] = *(const uint4*)(Wr + c * 8);
    }

    for (int k0 = 0; k0 < K; k0 += 64) {
        __syncthreads();
        #pragma unroll
        for (int c = 0; c < 4; ++c)
            *(uint4*)&As[arow * 72 + aoff + c * 8] = aR[c];
        #pragma unroll
        for (int c = 0; c < 2; ++c)
            *(uint4*)&Ws[wrow * 72 + woff + c * 8] = wR[c];

        if (k0 + 64 < K) {
            const unsigned short* Ar = A + (size_t)(m0 + arow) * K + k0 + 64 + aoff;
            #pragma unroll
            for (int c = 0; c < 4; ++c) aR[c] = *(const uint4*)(Ar + c * 8);
            const unsigned short* Wr = W + (size_t)(n0 + wrow) * K + k0 + 64 + woff;
            #pragma unroll
            for (int c = 0; c < 2; ++c) wR[c] = *(const uint4*)(Wr + c * 8);
        }
        __syncthreads();

        #pragma unroll
        for (int ks = 0; ks < 2; ++ks) {
            bf16x8 a0 = *(bf16x8*)&As[(w * 32 + lr) * 72 + ks * 32 + lq * 8];
            bf16x8 a1 = *(bf16x8*)&As[(w * 32 + 16 + lr) * 72 + ks * 32 + lq * 8];
            #pragma unroll
            for (int j = 0; j < 4; ++j) {
                bf16x8 bb = *(bf16x8*)&Ws[(j * 16 + lr) * 72 + ks * 32 + lq * 8];
                acc[0][j] = __builtin_amdgcn_mfma_f32_16x16x32_bf16(a0, bb, acc[0][j], 0, 0, 0);
                acc[1][j] = __builtin_amdgcn_mfma_f32_16x16x32_bf16(a1, bb, acc[1][j], 0, 0, 0);
            }
        }
    }

    float cs[4] = {}, cq[4] = {};
    #pragma unroll
    for (int m = 0; m < 2; ++m)
        #pragma unroll
        for (int j = 0; j < 4; ++j)
            #pragma unroll
            for (int r = 0; r < 4; ++r) {
                float v = acc[m][j][r];
                C[(size_t)(m0 + w * 32 + m * 16 + lq * 4 + r) * 256 + n0 + j * 16 + lr] = v;
                cs[j] += v;
                cq[j] += v * v;
            }
    #pragma unroll
    for (int j = 0; j < 4; ++j) {
        cs[j] += __shfl_xor(cs[j], 16); cs[j] += __shfl_xor(cs[j], 32);
        cq[j] += __shfl_xor(cq[j], 16); cq[j] += __shfl_xor(cq[j], 32);
    }
    __syncthreads();
    float* red = (float*)As;
    if (lq == 0) {
        #pragma unroll
        for (int j = 0; j < 4; ++j) {
            red[w * 128 + j * 16 + lr]      = cs[j];
            red[w * 128 + 64 + j * 16 + lr] = cq[j];
        }
    }
    __syncthreads();
    if (tid < 128) {
        int col = tid & 63, stat = tid >> 6;
        float t = red[stat * 64 + col] + red[128 + stat * 64 + col] +
                  red[256 + stat * 64 + col] + red[384 + stat * 64 + col];
        atomicAdd((stat ? gsumsq : gsum) + n0 + col, t);
    }
}

// ---------------------------------------------------------------------------
// Normalize + affine + LeakyReLU
// ---------------------------------------------------------------------------
__global__ __launch_bounds__(256) void bn_norm4(const float* __restrict__ p,
                                                const float* __restrict__ gsum,
                                                const float* __restrict__ gsumsq,
                                                const float* __restrict__ gamma,
                                                const float* __restrict__ beta,
                                                float* __restrict__ out) {
    int i = blockIdx.x * 256 + threadIdx.x;
    int c0 = (i * 4) & 255;
    const float invN = 1.0f / (float)NROWS;
    float4 pv = *(const float4*)(p + (size_t)i * 4);
    float vals[4] = {pv.x, pv.y, pv.z, pv.w};
    float res[4];
    #pragma unroll
    for (int k = 0; k < 4; ++k) {
        int c = c0 + k;
        float mean = gsum[c] * invN;
        float var  = gsumsq[c] * invN - mean * mean;
        float v = (vals[k] - mean) * rsqrtf(var + BN_EPS) * gamma[c] + beta[c];
        res[k] = v >= 0.f ? v : NEG_SLOPE * v;
    }
    float4 ov = {res[0], res[1], res[2], res[3]};
    *(float4*)(out + (size_t)i * 4) = ov;
}

// ---------------------------------------------------------------------------
// kernel_launch
// ---------------------------------------------------------------------------
extern "C" void kernel_launch(void* const* d_in, const int* in_sizes, int n_in,
                              void* d_out, int out_size, void* d_ws, size_t ws_size,
                              hipStream_t stream) {
    const float* x     = (const float*)d_in[0];
    const float* q     = (const float*)d_in[1];
    const float* Wq    = (const float*)d_in[2];
    const float* Wk    = (const float*)d_in[3];
    const float* Wv    = (const float*)d_in[4];
    const float* Wp    = (const float*)d_in[5];
    const float* gamma = (const float*)d_in[6];
    const float* beta  = (const float*)d_in[7];
    float* out = (float*)d_out;

    char* base = (char*)d_ws;
    unsigned short* Wqb  = (unsigned short*)(base + 0);          //  512x256 bf16
    unsigned short* Wkvb = (unsigned short*)(base + 262144);     // 1024x256 bf16
    unsigned short* Wpb  = (unsigned short*)(base + 786432);     //  256x512 bf16
    unsigned short* qh   = (unsigned short*)(base + 1048576);    // 16384x512 bf16
    unsigned short* khb  = (unsigned short*)(base + 17825792);   // 16384x512 bf16
    unsigned short* vTb  = (unsigned short*)(base + 34603008);   // [16,8,64,1024] bf16
    unsigned short* ob   = (unsigned short*)(base + 51380224);   // 16384x512 bf16
    float*          pbuf = (float*)        (base + 68157440);    // 16384x256 f32
    float*          stats= (float*)        (base + 84934656);    // 512 f32
    unsigned short* qbf  = (unsigned short*)(base + 84936704);   // 16384x256 bf16
    unsigned short* xbf  = (unsigned short*)(base + 93325312);   // 16384x256 bf16

    wcast<<<512, 256, 0, stream>>>(Wq, Wk, Wv, Wp, Wqb, Wkvb, Wpb, stats);
    qx_cast<<<8192, 256, 0, stream>>>(q, x, qbf, xbf);

    gemm_qkv5<<<dim3(12, 128), 256, 0, stream>>>(qbf, xbf, Wqb, Wkvb, qh, khb, vTb);

    attn_mfma7<<<dim3(8, 8, 16), 256, 0, stream>>>(qh, khb, vTb, ob);

    gemm_out<<<dim3(4, 128), 256, 0, stream>>>(ob, Wpb, pbuf, stats, stats + 256);

    bn_norm4<<<4096, 256, 0, stream>>>(pbuf, stats, stats + 256, gamma, beta, out);
}

// Round 13
// 245.827 us; speedup vs baseline: 1.0935x; 1.0625x over previous
//
#include <hip/hip_runtime.h>
#include <cstddef>

#define B_    16
#define SQ_   1024
#define SE_   1024
#define CIN_  256
#define DK_   64
#define H_    8
#define HD_   512
#define NROWS 16384
#define BN_EPS 1e-5f
#define NEG_SLOPE 0.01f

typedef __attribute__((ext_vector_type(8))) short bf16x8;
typedef __attribute__((ext_vector_type(4))) float f32x4;

__device__ __forceinline__ unsigned short f2bf(float f) {  // RNE
    unsigned int u = __float_as_uint(f);
    return (unsigned short)((u + 0x7FFFu + ((u >> 16) & 1u)) >> 16);
}

#if __has_builtin(__builtin_amdgcn_perm)
__device__ __forceinline__ unsigned int pack_trunc(float lo, float hi) {
    return __builtin_amdgcn_perm(__float_as_uint(hi), __float_as_uint(lo), 0x07060302u);
}
#else
__device__ __forceinline__ unsigned int pack_trunc(float lo, float hi) {
    return (__float_as_uint(lo) >> 16) | (__float_as_uint(hi) & 0xFFFF0000u);
}
#endif

#if __has_builtin(__builtin_amdgcn_exp2f)
#define EXP2F(x) __builtin_amdgcn_exp2f(x)
#else
#define EXP2F(x) exp2f(x)
#endif

__device__ __forceinline__ ushort4 pack4(f32x4 v) {
    ushort4 p;
    p.x = f2bf(v[0]); p.y = f2bf(v[1]);
    p.z = f2bf(v[2]); p.w = f2bf(v[3]);
    return p;
}

// ---------------------------------------------------------------------------
// Weight casts (one dispatch). Wq gets 0.125*log2(e) folded in.
// Blocks 0..1 also zero the BN stats accumulators.
// ---------------------------------------------------------------------------
__global__ __launch_bounds__(256) void wcast(const float* __restrict__ Wq,
                                             const float* __restrict__ Wk,
                                             const float* __restrict__ Wv,
                                             const float* __restrict__ Wp,
                                             unsigned short* __restrict__ dWq,
                                             unsigned short* __restrict__ dWkv,
                                             unsigned short* __restrict__ dWp,
                                             float* __restrict__ stats) {
    if (blockIdx.x < 2) stats[blockIdx.x * 256 + threadIdx.x] = 0.f;
    int i = blockIdx.x * 256 + threadIdx.x;
    int which = i >> 15, off = i & 32767;
    const float* s; unsigned short* d; float sc = 1.0f;
    if (which == 0)      { s = Wq; d = dWq; sc = 0.18033688011112042f; }
    else if (which == 1) { s = Wk; d = dWkv; }
    else if (which == 2) { s = Wv; d = dWkv + 131072; }
    else                 { s = Wp; d = dWp; }
    float4 v = *(const float4*)(s + (size_t)off * 4);
    ushort4 pk;
    pk.x = f2bf(v.x * sc); pk.y = f2bf(v.y * sc);
    pk.z = f2bf(v.z * sc); pk.w = f2bf(v.w * sc);
    *(ushort4*)(d + (size_t)off * 4) = pk;
}

// ---------------------------------------------------------------------------
// Fused Q+KV projection GEMM, 128x128 tile, BK=64, f32 A with cast fused
// into LDS staging (no qbf/xbf intermediate), register prefetch.
// grid (12,128): bx<4 Q, 4..7 K, 8..11 V.
// Q/K: transposed compute mfma(W,A); V: normal compute (vT layout).
// Epilogue: LDS-staged full-line coalesced stores (R12 pattern).
// ---------------------------------------------------------------------------
__global__ __launch_bounds__(256) void gemm_qkv6(const float* __restrict__ qsrc,
                                                 const float* __restrict__ xsrc,
                                                 const unsigned short* __restrict__ Wqb,
                                                 const unsigned short* __restrict__ Wkvb,
                                                 unsigned short* __restrict__ qh,
                                                 unsigned short* __restrict__ khb,
                                                 unsigned short* __restrict__ vTb) {
    __shared__ __align__(16) unsigned short smem[18432];    // 36 KB
    unsigned short* As = smem;                              // 128*72
    unsigned short* Ws = smem + 9216;                       // 128*72
    unsigned short* Cs = smem;                              // epilogue: 128*144

    const int tid = threadIdx.x;
    const int w = tid >> 6, l = tid & 63, lq = l >> 4, lr = l & 15;
    const int bx = blockIdx.x;
    const bool isQ = bx < 4;
    const bool isV = bx >= 8;
    const float* A = isQ ? qsrc : xsrc;
    const unsigned short* W = isQ ? Wqb : Wkvb;
    const int n0 = (isQ ? bx : bx - 4) * 128;
    const int m0 = blockIdx.y * 128;
    const int K = 256;

    const int srow = tid >> 1, soff = (tid & 1) * 32;   // 32 elems/thread

    f32x4 acc[2][8] = {};
    uint4 aR[8], wR[4];

    {
        const float* Ar = A + (size_t)(m0 + srow) * K + soff;
        #pragma unroll
        for (int c = 0; c < 8; ++c) aR[c] = *(const uint4*)(Ar + c * 4);
        const unsigned short* Wr = W + (size_t)(n0 + srow) * K + soff;
        #pragma unroll
        for (int c = 0; c < 4; ++c) wR[c] = *(const uint4*)(Wr + c * 8);
    }

    for (int k0 = 0; k0 < K; k0 += 64) {
        __syncthreads();
        #pragma unroll
        for (int c = 0; c < 4; ++c) {
            float4 u0 = *(float4*)&aR[2 * c];
            float4 u1 = *(float4*)&aR[2 * c + 1];
            uint4 pk;
            pk.x = pack_trunc(u0.x, u0.y);
            pk.y = pack_trunc(u0.z, u0.w);
            pk.z = pack_trunc(u1.x, u1.y);
            pk.w = pack_trunc(u1.z, u1.w);
            *(uint4*)&As[srow * 72 + soff + c * 8] = pk;
            *(uint4*)&Ws[srow * 72 + soff + c * 8] = wR[c];
        }
        if (k0 + 64 < K) {
            const float* Ar = A + (size_t)(m0 + srow) * K + k0 + 64 + soff;
            #pragma unroll
            for (int c = 0; c < 8; ++c) aR[c] = *(const uint4*)(Ar + c * 4);
            const unsigned short* Wr = W + (size_t)(n0 + srow) * K + k0 + 64 + soff;
            #pragma unroll
            for (int c = 0; c < 4; ++c) wR[c] = *(const uint4*)(Wr + c * 8);
        }
        __syncthreads();

        if (!isV) {   // transposed compute: D[n][m]
            #pragma unroll
            for (int ks = 0; ks < 2; ++ks) {
                bf16x8 a0 = *(bf16x8*)&As[(w * 32 + lr) * 72 + ks * 32 + lq * 8];
                bf16x8 a1 = *(bf16x8*)&As[(w * 32 + 16 + lr) * 72 + ks * 32 + lq * 8];
                #pragma unroll
                for (int j = 0; j < 8; ++j) {
                    bf16x8 bb = *(bf16x8*)&Ws[(j * 16 + lr) * 72 + ks * 32 + lq * 8];
                    acc[0][j] = __builtin_amdgcn_mfma_f32_16x16x32_bf16(bb, a0, acc[0][j], 0, 0, 0);
                    acc[1][j] = __builtin_amdgcn_mfma_f32_16x16x32_bf16(bb, a1, acc[1][j], 0, 0, 0);
                }
            }
        } else {      // normal compute: D[m][n]
            #pragma unroll
            for (int ks = 0; ks < 2; ++ks) {
                bf16x8 a0 = *(bf16x8*)&As[(w * 32 + lr) * 72 + ks * 32 + lq * 8];
                bf16x8 a1 = *(bf16x8*)&As[(w * 32 + 16 + lr) * 72 + ks * 32 + lq * 8];
                #pragma unroll
                for (int j = 0; j < 8; ++j) {
                    bf16x8 bb = *(bf16x8*)&Ws[(j * 16 + lr) * 72 + ks * 32 + lq * 8];
                    acc[0][j] = __builtin_amdgcn_mfma_f32_16x16x32_bf16(a0, bb, acc[0][j], 0, 0, 0);
                    acc[1][j] = __builtin_amdgcn_mfma_f32_16x16x32_bf16(a1, bb, acc[1][j], 0, 0, 0);
                }
            }
        }
    }

    // ---- Epilogue: LDS staging, then full-line coalesced stores ----
    __syncthreads();
    const int c16 = tid & 15;
    const int rb  = tid >> 4;
    if (!isV) {
        #pragma unroll
        for (int mf = 0; mf < 2; ++mf)
            #pragma unroll
            for (int j = 0; j < 8; ++j)
                *(ushort4*)&Cs[(w * 32 + mf * 16 + lr) * 144 + j * 16 + lq * 4] =
                    pack4(acc[mf][j]);
        __syncthreads();
        unsigned short* C = isQ ? qh : khb;
        #pragma unroll
        for (int it = 0; it < 8; ++it) {
            int r = it * 16 + rb;
            *(uint4*)(C + (size_t)(m0 + r) * 512 + n0 + c16 * 8) =
                *(const uint4*)(Cs + r * 144 + c16 * 8);
        }
    } else {
        #pragma unroll
        for (int mf = 0; mf < 2; ++mf)
            #pragma unroll
            for (int j = 0; j < 8; ++j)
                *(ushort4*)&Cs[(j * 16 + lr) * 144 + w * 32 + mf * 16 + lq * 4] =
                    pack4(acc[mf][j]);
        __syncthreads();
        const int bb = m0 >> 10, t0 = m0 & 1023;
        #pragma unroll
        for (int it = 0; it < 8; ++it) {
            int el = it * 16 + rb;
            int colv = n0 - 512 + el;
            int hh = colv >> 6, e = colv & 63;
            *(uint4*)(vTb + (size_t)((bb * 8 + hh) * 64 + e) * 1024 + t0 + c16 * 8) =
                *(const uint4*)(Cs + el * 144 + c16 * 8);
        }
    }
}

// ---------------------------------------------------------------------------
// MFMA flash attention v8: 256 q-rows/block, 64 q-rows/wave (mm=0..3).
// Doubles MFMA per staged K/V tile; K-fragment reads amortized 4x over mm
// -> DS cycles per MFMA ~7 vs ~11. LDS: Ks+Vs 18KB + Ps 36KB = 54KB,
// 2 blocks/CU. S^T mfma(K,Q), no-max exp2 softmax, packed b64 P writes,
// transposed PV mfma(V,P), per-lane scalar inv.
// ---------------------------------------------------------------------------
__global__ __launch_bounds__(256) void attn_mfma8(const unsigned short* __restrict__ qh,
                                                  const unsigned short* __restrict__ kh,
                                                  const unsigned short* __restrict__ vT,
                                                  unsigned short* __restrict__ o) {
    __shared__ __align__(16) unsigned short Ks[64 * 72];      // [key][d]   9.2 KB
    __shared__ __align__(16) unsigned short Vs[64 * 72];      // [e][t]     9.2 KB
    __shared__ __align__(16) unsigned short Ps[4][64 * 72];   // per-wave P 36.9 KB

    const int tid = threadIdx.x;
    const int w = tid >> 6, l = tid & 63, lq = l >> 4, lr = l & 15;
    const int q0 = blockIdx.x * 256, h = blockIdx.y, b = blockIdx.z;

    // Q fragments: lane lr holds row m = mm*16+lr, elems k = lq*8+j (+32)
    bf16x8 qf[4][2];
    #pragma unroll
    for (int mm = 0; mm < 4; ++mm) {
        const unsigned short* qr =
            qh + (size_t)(b * SQ_ + q0 + w * 64 + mm * 16 + lr) * HD_ + h * DK_;
        qf[mm][0] = *(const bf16x8*)(qr + lq * 8);
        qf[mm][1] = *(const bf16x8*)(qr + 32 + lq * 8);
    }

    const unsigned short* kb = kh + (size_t)(b * SE_) * HD_ + h * DK_;
    const unsigned short* vb = vT + (size_t)((b * 8 + h) * 64) * 1024;

    const int se = tid >> 3;        // 0..31
    const int sc = (tid & 7) * 8;

    float l_i[4] = {};              // per-lane partial row-sum; m = mm*16 + lr
    f32x4 oacc[4][4] = {};          // [mm][e-strip j]; D[e][m]
    unsigned short* Pw = Ps[w];

    for (int t0 = 0; t0 < SE_; t0 += 64) {
        __syncthreads();
        #pragma unroll
        for (int ps = 0; ps < 2; ++ps) {
            int rr = se + ps * 32;
            *(uint4*)&Ks[rr * 72 + sc] = *(const uint4*)(kb + (size_t)(t0 + rr) * HD_ + sc);
            *(uint4*)&Vs[rr * 72 + sc] = *(const uint4*)(vb + (size_t)rr * 1024 + t0 + sc);
        }
        __syncthreads();

        // S^T tiles: sT[tt][mm]; C row = t (lq*4+r), col = m (lr).
        // kf read once per (ks,tt), reused across 4 mm.
        f32x4 sT[4][4] = {};
        #pragma unroll
        for (int ks = 0; ks < 2; ++ks)
            #pragma unroll
            for (int tt = 0; tt < 4; ++tt) {
                bf16x8 kf = *(bf16x8*)&Ks[(tt * 16 + lr) * 72 + ks * 32 + lq * 8];
                #pragma unroll
                for (int mm = 0; mm < 4; ++mm)
                    sT[tt][mm] = __builtin_amdgcn_mfma_f32_16x16x32_bf16(kf, qf[mm][ks], sT[tt][mm], 0, 0, 0);
            }

        // exp2 + lane-local l accum + packed b64 P write (4 consecutive t)
        #pragma unroll
        for (int mm = 0; mm < 4; ++mm)
            #pragma unroll
            for (int tt = 0; tt < 4; ++tt) {
                float e0 = EXP2F(sT[tt][mm][0]);
                float e1 = EXP2F(sT[tt][mm][1]);
                float e2 = EXP2F(sT[tt][mm][2]);
                float e3 = EXP2F(sT[tt][mm][3]);
                l_i[mm] += (e0 + e1) + (e2 + e3);
                uint2 pk;
                pk.x = pack_trunc(e0, e1);
                pk.y = pack_trunc(e2, e3);
                *(uint2*)&Pw[(mm * 16 + lr) * 72 + tt * 16 + lq * 4] = pk;
            }
        asm volatile("s_waitcnt lgkmcnt(0)" ::: "memory");   // wave-local round trip

        // PV transposed: oacc[mm][j] = V_strip_j . P_mm^T -> D[e][m].
        // vf read once per (ks,j), reused across 4 mm.
        #pragma unroll
        for (int ks = 0; ks < 2; ++ks) {
            bf16x8 pf[4];
            #pragma unroll
            for (int mm = 0; mm < 4; ++mm)
                pf[mm] = *(bf16x8*)&Pw[(mm * 16 + lr) * 72 + ks * 32 + lq * 8];
            #pragma unroll
            for (int j = 0; j < 4; ++j) {
                bf16x8 vf = *(bf16x8*)&Vs[(j * 16 + lr) * 72 + ks * 32 + lq * 8];
                #pragma unroll
                for (int mm = 0; mm < 4; ++mm)
                    oacc[mm][j] = __builtin_amdgcn_mfma_f32_16x16x32_bf16(vf, pf[mm], oacc[mm][j], 0, 0, 0);
            }
        }
    }

    float inv[4];
    #pragma unroll
    for (int mm = 0; mm < 4; ++mm) {
        float t = l_i[mm];
        t += __shfl_xor(t, 16);
        t += __shfl_xor(t, 32);
        inv[mm] = 1.0f / t;
    }

    // o store: D row = e_local = lq*4+r (4 consecutive e), col = m = lr.
    #pragma unroll
    for (int mm = 0; mm < 4; ++mm)
        #pragma unroll
        for (int j = 0; j < 4; ++j) {
            f32x4 v = oacc[mm][j];
            v[0] *= inv[mm]; v[1] *= inv[mm]; v[2] *= inv[mm]; v[3] *= inv[mm];
            *(ushort4*)&o[(size_t)(b * SQ_ + q0 + w * 64 + mm * 16 + lr) * HD_ +
                          h * DK_ + j * 16 + lq * 4] = pack4(v);
        }
}

// ---------------------------------------------------------------------------
// Output projection: p = o @ Wp^T (bf16 in, f32 out) + fused BN partials.
// 128x64 tiles, K=512, register prefetch.
// ---------------------------------------------------------------------------
__global__ __launch_bounds__(256) void gemm_out(const unsigned short* __restrict__ A,
                                                const unsigned short* __restrict__ W,
                                                float* __restrict__ C,
                                                float* __restrict__ gsum,
                                                float* __restrict__ gsumsq) {
    __shared__ __align__(16) unsigned short As[128 * 72];
    __shared__ __align__(16) unsigned short Ws[64 * 72];
    const int tid = threadIdx.x;
    const int w = tid >> 6, l = tid & 63, lq = l >> 4, lr = l & 15;
    const int n0 = blockIdx.x * 64, m0 = blockIdx.y * 128;
    const int K = 512;

    const int arow = tid >> 1, aoff = (tid & 1) * 32;
    const int wrow = tid >> 2, woff = (tid & 3) * 16;

    f32x4 acc[2][4] = {};
    uint4 aR[4], wR[2];

    {
        const unsigned short* Ar = A + (size_t)(m0 + arow) * K + aoff;
        #pragma unroll
        for (int c = 0; c < 4; ++c) aR[c] = *(const uint4*)(Ar + c * 8);
        const unsigned short* Wr = W + (size_t)(n0 + wrow) * K + woff;
        #pragma unroll
        for (int c = 0; c < 2; ++c) wR[c] = *(const uint4*)(Wr + c * 8);
    }

    for (int k0 = 0; k0 < K; k0 += 64) {
        __syncthreads();
        #pragma unroll
        for (int c = 0; c < 4; ++c)
            *(uint4*)&As[arow * 72 + aoff + c * 8] = aR[c];
        #pragma unroll
        for (int c = 0; c < 2; ++c)
            *(uint4*)&Ws[wrow * 72 + woff + c * 8] = wR[c];

        if (k0 + 64 < K) {
            const unsigned short* Ar = A + (size_t)(m0 + arow) * K + k0 + 64 + aoff;
            #pragma unroll
            for (int c = 0; c < 4; ++c) aR[c] = *(const uint4*)(Ar + c * 8);
            const unsigned short* Wr = W + (size_t)(n0 + wrow) * K + k0 + 64 + woff;
            #pragma unroll
            for (int c = 0; c < 2; ++c) wR[c] = *(const uint4*)(Wr + c * 8);
        }
        __syncthreads();

        #pragma unroll
        for (int ks = 0; ks < 2; ++ks) {
            bf16x8 a0 = *(bf16x8*)&As[(w * 32 + lr) * 72 + ks * 32 + lq * 8];
            bf16x8 a1 = *(bf16x8*)&As[(w * 32 + 16 + lr) * 72 + ks * 32 + lq * 8];
            #pragma unroll
            for (int j = 0; j < 4; ++j) {
                bf16x8 bb = *(bf16x8*)&Ws[(j * 16 + lr) * 72 + ks * 32 + lq * 8];
                acc[0][j] = __builtin_amdgcn_mfma_f32_16x16x32_bf16(a0, bb, acc[0][j], 0, 0, 0);
                acc[1][j] = __builtin_amdgcn_mfma_f32_16x16x32_bf16(a1, bb, acc[1][j], 0, 0, 0);
            }
        }
    }

    float cs[4] = {}, cq[4] = {};
    #pragma unroll
    for (int m = 0; m < 2; ++m)
        #pragma unroll
        for (int j = 0; j < 4; ++j)
            #pragma unroll
            for (int r = 0; r < 4; ++r) {
                float v = acc[m][j][r];
                C[(size_t)(m0 + w * 32 + m * 16 + lq * 4 + r) * 256 + n0 + j * 16 + lr] = v;
                cs[j] += v;
                cq[j] += v * v;
            }
    #pragma unroll
    for (int j = 0; j < 4; ++j) {
        cs[j] += __shfl_xor(cs[j], 16); cs[j] += __shfl_xor(cs[j], 32);
        cq[j] += __shfl_xor(cq[j], 16); cq[j] += __shfl_xor(cq[j], 32);
    }
    __syncthreads();
    float* red = (float*)As;
    if (lq == 0) {
        #pragma unroll
        for (int j = 0; j < 4; ++j) {
            red[w * 128 + j * 16 + lr]      = cs[j];
            red[w * 128 + 64 + j * 16 + lr] = cq[j];
        }
    }
    __syncthreads();
    if (tid < 128) {
        int col = tid & 63, stat = tid >> 6;
        float t = red[stat * 64 + col] + red[128 + stat * 64 + col] +
                  red[256 + stat * 64 + col] + red[384 + stat * 64 + col];
        atomicAdd((stat ? gsumsq : gsum) + n0 + col, t);
    }
}

// ---------------------------------------------------------------------------
// Normalize + affine + LeakyReLU
// ---------------------------------------------------------------------------
__global__ __launch_bounds__(256) void bn_norm4(const float* __restrict__ p,
                                                const float* __restrict__ gsum,
                                                const float* __restrict__ gsumsq,
                                                const float* __restrict__ gamma,
                                                const float* __restrict__ beta,
                                                float* __restrict__ out) {
    int i = blockIdx.x * 256 + threadIdx.x;
    int c0 = (i * 4) & 255;
    const float invN = 1.0f / (float)NROWS;
    float4 pv = *(const float4*)(p + (size_t)i * 4);
    float vals[4] = {pv.x, pv.y, pv.z, pv.w};
    float res[4];
    #pragma unroll
    for (int k = 0; k < 4; ++k) {
        int c = c0 + k;
        float mean = gsum[c] * invN;
        float var  = gsumsq[c] * invN - mean * mean;
        float v = (vals[k] - mean) * rsqrtf(var + BN_EPS) * gamma[c] + beta[c];
        res[k] = v >= 0.f ? v : NEG_SLOPE * v;
    }
    float4 ov = {res[0], res[1], res[2], res[3]};
    *(float4*)(out + (size_t)i * 4) = ov;
}

// ---------------------------------------------------------------------------
// kernel_launch
// ---------------------------------------------------------------------------
extern "C" void kernel_launch(void* const* d_in, const int* in_sizes, int n_in,
                              void* d_out, int out_size, void* d_ws, size_t ws_size,
                              hipStream_t stream) {
    const float* x     = (const float*)d_in[0];
    const float* q     = (const float*)d_in[1];
    const float* Wq    = (const float*)d_in[2];
    const float* Wk    = (const float*)d_in[3];
    const float* Wv    = (const float*)d_in[4];
    const float* Wp    = (const float*)d_in[5];
    const float* gamma = (const float*)d_in[6];
    const float* beta  = (const float*)d_in[7];
    float* out = (float*)d_out;

    char* base = (char*)d_ws;
    unsigned short* Wqb  = (unsigned short*)(base + 0);          //  512x256 bf16
    unsigned short* Wkvb = (unsigned short*)(base + 262144);     // 1024x256 bf16
    unsigned short* Wpb  = (unsigned short*)(base + 786432);     //  256x512 bf16
    unsigned short* qh   = (unsigned short*)(base + 1048576);    // 16384x512 bf16
    unsigned short* khb  = (unsigned short*)(base + 17825792);   // 16384x512 bf16
    unsigned short* vTb  = (unsigned short*)(base + 34603008);   // [16,8,64,1024] bf16
    unsigned short* ob   = (unsigned short*)(base + 51380224);   // 16384x512 bf16
    float*          pbuf = (float*)        (base + 68157440);    // 16384x256 f32
    float*          stats= (float*)        (base + 84934656);    // 512 f32

    wcast<<<512, 256, 0, stream>>>(Wq, Wk, Wv, Wp, Wqb, Wkvb, Wpb, stats);

    gemm_qkv6<<<dim3(12, 128), 256, 0, stream>>>(q, x, Wqb, Wkvb, qh, khb, vTb);

    attn_mfma8<<<dim3(4, 8, 16), 256, 0, stream>>>(qh, khb, vTb, ob);

    gemm_out<<<dim3(4, 128), 256, 0, stream>>>(ob, Wpb, pbuf, stats, stats + 256);

    bn_norm4<<<4096, 256, 0, stream>>>(pbuf, stats, stats + 256, gamma, beta, out);
}